// Round 8
// baseline (658.584 us; speedup 1.0000x reference)
//
#include <hip/hip_runtime.h>
#include <hip/hip_cooperative_groups.h>
#include <hip/hip_fp16.h>
#include <cstdint>
#include <cstddef>

// ---------------------------------------------------------------------------
// SelfAttentionV2: out = softmax((x Wq + bq)(x Wk + bk)^T / 32) (x Wv + bv)
// N=4096, D=1024. fp32 in/out, fp16 MFMA internal.
// R8: cooperative mega-kernel with occupancy-queried grid size (stride-G task
//     loops make any G correct) + checked launch + fallback to the proven R6
//     5-dispatch path. Phase math identical to R6 (2-wave 128x128 swizzled-LDS
//     core, fused exp+partial-rowsums, PV split-K=4, XCD banding).
// ---------------------------------------------------------------------------

#define NTOK 4096
#define DIM  1024

typedef _Float16 half8  __attribute__((ext_vector_type(8)));
typedef _Float16 half4v __attribute__((ext_vector_type(4)));
typedef float    floatx4 __attribute__((ext_vector_type(4)));

#define GLOBAL_AS __attribute__((address_space(1)))
#define LDS_AS    __attribute__((address_space(3)))

__device__ __forceinline__ void lds_load16(const _Float16* gsrc, _Float16* ldst) {
    __builtin_amdgcn_global_load_lds((GLOBAL_AS void*)gsrc, (LDS_AS void*)ldst, 16, 0, 0);
}

// ---------------------------------------------------------------------------
// 2-WAVE NT GEMM core: block tile 128(m) x 128(n), BK=64, swizzled LDS.
// (verbatim from R6; verified absmax 9.77e-4)
// ---------------------------------------------------------------------------
__device__ __forceinline__ void gemm_core2(const _Float16* __restrict__ A,
                                           const _Float16* __restrict__ B,
                                           int K, int lda, int ldb,
                                           int m0, int n0,
                                           _Float16* ldsA, _Float16* ldsB,
                                           floatx4 acc[4][8])
{
    const int t    = threadIdx.x;    // 0..127
    const int lane = t & 63;
    const int wid  = t >> 6;
    const int wm   = wid * 64;
    const int lrow = lane & 15;
    const int q    = lane >> 4;
    const int xk   = lrow & 7;

    const _Float16* asrc[8]; _Float16* adst[8];
    const _Float16* bsrc[8]; _Float16* bdst[8];
    #pragma unroll
    for (int i = 0; i < 8; ++i) {
        const int p = t + 128 * i, row = p >> 3;
        const int col = ((p & 7) ^ (row & 7)) * 8;
        asrc[i] = A + (size_t)(m0 + row) * lda + col;
        adst[i] = ldsA + p * 8;
        bsrc[i] = B + (size_t)(n0 + row) * ldb + col;
        bdst[i] = ldsB + p * 8;
    }

    const _Float16* fa = ldsA + (wm + lrow) * 64;
    const _Float16* fb = ldsB + lrow * 64;

    for (int k0 = 0; k0 < K; k0 += 64) {
        #pragma unroll
        for (int i = 0; i < 8; ++i) lds_load16(asrc[i] + k0, adst[i]);
        #pragma unroll
        for (int i = 0; i < 8; ++i) lds_load16(bsrc[i] + k0, bdst[i]);
        __syncthreads();

        #pragma unroll
        for (int s = 0; s < 2; ++s) {
            const int co = (((s * 4 + q) ^ xk) * 8);
            half8 af[4], bf[8];
            #pragma unroll
            for (int i = 0; i < 4; ++i) af[i] = *(const half8*)(fa + i * 1024 + co);
            #pragma unroll
            for (int i = 0; i < 8; ++i) bf[i] = *(const half8*)(fb + i * 1024 + co);
            #pragma unroll
            for (int ni = 0; ni < 8; ++ni)
                #pragma unroll
                for (int mi = 0; mi < 4; ++mi)
                    acc[mi][ni] = __builtin_amdgcn_mfma_f32_16x16x32_f16(
                        af[mi], bf[ni], acc[mi][ni], 0, 0, 0);
        }
        __syncthreads();
    }
}

// ---------------------------------------------------------------------------
// Phase task bodies (shared by mega kernel and fallback kernels).
// All assume blockDim.x == 128.
// ---------------------------------------------------------------------------
__device__ __forceinline__ void prep_x_body(int gsize, int gid,
                                            const float* __restrict__ x,
                                            _Float16* __restrict__ xh)
{
    for (size_t idx = gid; idx < (size_t)NTOK * DIM / 4; idx += gsize) {
        size_t i = idx * 4;
        float4 v = *(const float4*)(x + i);
        half4v h;
        h[0] = (_Float16)v.x; h[1] = (_Float16)v.y;
        h[2] = (_Float16)v.z; h[3] = (_Float16)v.w;
        *(half4v*)(xh + i) = h;
    }
}

__device__ __forceinline__ void prep_w_body(int nblocks, int b,
                                            const float* __restrict__ W0,
                                            const float* __restrict__ W1,
                                            const float* __restrict__ W2,
                                            _Float16* __restrict__ Wt,
                                            float* tile /* >= 32*33 floats */)
{
    const int t = threadIdx.x;
    const int tx = t & 31, ty = t >> 5;   // ty in [0,4)
    for (int w = b; w < 3072; w += nblocks) {
        const int z = w >> 10, r = w & 1023;
        const int nb = (r & 31) * 32, kb = (r >> 5) * 32;
        const float* W = (z == 0) ? W0 : (z == 1) ? W1 : W2;
        _Float16* outw = Wt + (size_t)z * DIM * DIM;
        #pragma unroll
        for (int i = 0; i < 32; i += 4)
            tile[(ty + i) * 33 + tx] = W[(size_t)(kb + ty + i) * DIM + nb + tx];
        __syncthreads();
        #pragma unroll
        for (int i = 0; i < 32; i += 4)
            outw[(size_t)(nb + ty + i) * DIM + kb + tx] =
                (_Float16)tile[tx * 33 + ty + i];
        __syncthreads();
    }
}

__device__ __forceinline__ void task_qkv(int task,
                                         const _Float16* __restrict__ xh,
                                         const _Float16* __restrict__ Wt,
                                         const float* __restrict__ bq,
                                         const float* __restrict__ bk,
                                         const float* __restrict__ bv,
                                         _Float16* __restrict__ qh,
                                         _Float16* __restrict__ kh,
                                         _Float16* __restrict__ vt,
                                         _Float16* ldsA, _Float16* ldsB)
{
    const int z   = task >> 8;       // 0,1,2
    const int g   = task & 255;
    const int xcd = g & 7;
    const int j   = g >> 3;          // 0..31

    const _Float16* A; const _Float16* B;
    const float* bias; _Float16* outm;
    int m0, n0, ldc; bool bias_by_row;

    if (z < 2) {
        const int mt = xcd * 4 + (j & 3);   // 32 m-tiles
        const int nt = j >> 2;              // 8 n-tiles
        m0 = mt * 128; n0 = nt * 128; ldc = DIM; bias_by_row = false;
        A = xh;
        B = (z == 0) ? Wt : Wt + DIM * DIM;
        bias = (z == 0) ? bq : bk;
        outm = (z == 0) ? qh : kh;
    } else {
        m0 = xcd * 128; n0 = j * 128; ldc = NTOK; bias_by_row = true;
        A = Wt + 2 * DIM * DIM; B = xh; bias = bv; outm = vt;
    }

    floatx4 acc[4][8];
    #pragma unroll
    for (int mi = 0; mi < 4; ++mi)
        #pragma unroll
        for (int ni = 0; ni < 8; ++ni)
            #pragma unroll
            for (int r = 0; r < 4; ++r) acc[mi][ni][r] = 0.0f;

    gemm_core2(A, B, DIM, DIM, DIM, m0, n0, ldsA, ldsB, acc);

    const int lane = threadIdx.x & 63;
    const int wm   = (threadIdx.x >> 6) * 64;
    const int lrow = lane & 15;
    const int q    = lane >> 4;
    #pragma unroll
    for (int mi = 0; mi < 4; ++mi) {
        #pragma unroll
        for (int ni = 0; ni < 8; ++ni) {
            const int gm = m0 + wm + mi * 16 + q * 4;
            const int gn = n0 + ni * 16 + lrow;
            const float bcol = bias_by_row ? 0.0f : bias[gn];
            #pragma unroll
            for (int r = 0; r < 4; ++r) {
                float bb = bias_by_row ? bias[gm + r] : bcol;
                outm[(size_t)(gm + r) * ldc + gn] = (_Float16)(acc[mi][ni][r] + bb);
            }
        }
    }
}

__device__ __forceinline__ void task_s(int task,
                                       const _Float16* __restrict__ qh,
                                       const _Float16* __restrict__ kh,
                                       _Float16* __restrict__ P,
                                       float* __restrict__ rowsum_part,
                                       _Float16* ldsA, _Float16* ldsB)
{
    const int xcd = task & 7;
    const int j   = task >> 3;           // 0..127
    const int mt  = xcd * 4 + (j & 3);   // 32 m-tiles
    const int nt  = j >> 2;              // 32 n-tiles
    const int m0  = mt * 128;
    const int n0  = nt * 128;

    floatx4 acc[4][8];
    #pragma unroll
    for (int mi = 0; mi < 4; ++mi)
        #pragma unroll
        for (int ni = 0; ni < 8; ++ni)
            #pragma unroll
            for (int r = 0; r < 4; ++r) acc[mi][ni][r] = 0.0f;

    gemm_core2(qh, kh, DIM, DIM, DIM, m0, n0, ldsA, ldsB, acc);

    const int lane = threadIdx.x & 63;
    const int wm   = (threadIdx.x >> 6) * 64;
    const int lrow = lane & 15;
    const int q    = lane >> 4;

    #pragma unroll
    for (int mi = 0; mi < 4; ++mi) {
        #pragma unroll
        for (int r = 0; r < 4; ++r) {
            const int gm = m0 + wm + mi * 16 + q * 4 + r;
            float rs = 0.0f;
            #pragma unroll
            for (int ni = 0; ni < 8; ++ni) {
                const int gn = n0 + ni * 16 + lrow;
                float e = __expf(acc[mi][ni][r] * 0.03125f - 8.0f);
                P[(size_t)gm * NTOK + gn] = (_Float16)e;
                rs += e;
            }
            rs += __shfl_xor(rs, 1, 64);
            rs += __shfl_xor(rs, 2, 64);
            rs += __shfl_xor(rs, 4, 64);
            rs += __shfl_xor(rs, 8, 64);
            if (lrow == 0) rowsum_part[(size_t)gm * 32 + nt] = rs;
        }
    }
}

__device__ __forceinline__ void task_pv(int task,
                                        const _Float16* __restrict__ P,
                                        const _Float16* __restrict__ vt,
                                        float* __restrict__ out,
                                        _Float16* __restrict__ P1,
                                        _Float16* __restrict__ P2,
                                        _Float16* __restrict__ P3,
                                        _Float16* ldsA, _Float16* ldsB)
{
    const int z   = task >> 8;       // 0..3
    const int g   = task & 255;
    const int xcd = g & 7;
    const int j   = g >> 3;          // 0..31
    const int mt  = xcd * 4 + (j & 3);   // 32 m-tiles
    const int nt  = j >> 2;              // 8 n-tiles
    const int m0  = mt * 128;
    const int n0  = nt * 128;
    const int kstart = z * (NTOK / 4);

    floatx4 acc[4][8];
    #pragma unroll
    for (int mi = 0; mi < 4; ++mi)
        #pragma unroll
        for (int ni = 0; ni < 8; ++ni)
            #pragma unroll
            for (int r = 0; r < 4; ++r) acc[mi][ni][r] = 0.0f;

    gemm_core2(P + kstart, vt + kstart, NTOK / 4, NTOK, NTOK, m0, n0,
               ldsA, ldsB, acc);

    const int lane = threadIdx.x & 63;
    const int wm   = (threadIdx.x >> 6) * 64;
    const int lrow = lane & 15;
    const int q    = lane >> 4;

    _Float16* ph = (z == 1) ? P1 : (z == 2) ? P2 : P3;
    #pragma unroll
    for (int mi = 0; mi < 4; ++mi) {
        #pragma unroll
        for (int ni = 0; ni < 8; ++ni) {
            const int gm = m0 + wm + mi * 16 + q * 4;
            const int gn = n0 + ni * 16 + lrow;
            #pragma unroll
            for (int r = 0; r < 4; ++r) {
                if (z == 0) out[(size_t)(gm + r) * DIM + gn] = acc[mi][ni][r];
                else        ph[(size_t)(gm + r) * DIM + gn] = (_Float16)acc[mi][ni][r];
            }
        }
    }
}

__device__ __forceinline__ void task_addinv(int row,
                                            float* __restrict__ out,
                                            const _Float16* __restrict__ P1,
                                            const _Float16* __restrict__ P2,
                                            const _Float16* __restrict__ P3,
                                            const float* __restrict__ rowsum_part)
{
    const int t = threadIdx.x;
    float v = rowsum_part[(size_t)row * 32 + (t & 31)];
    v += __shfl_xor(v, 16, 64);
    v += __shfl_xor(v, 8, 64);
    v += __shfl_xor(v, 4, 64);
    v += __shfl_xor(v, 2, 64);
    v += __shfl_xor(v, 1, 64);
    const float inv = 1.0f / v;

    size_t i = (size_t)row * DIM + (size_t)t * 8;
    #pragma unroll
    for (int h = 0; h < 2; ++h) {
        size_t ii = i + h * 4;
        float4 a = *(const float4*)(out + ii);
        half4v b1 = *(const half4v*)(P1 + ii);
        half4v b2 = *(const half4v*)(P2 + ii);
        half4v b3 = *(const half4v*)(P3 + ii);
        a.x = (a.x + (float)b1[0] + (float)b2[0] + (float)b3[0]) * inv;
        a.y = (a.y + (float)b1[1] + (float)b2[1] + (float)b3[1]) * inv;
        a.z = (a.z + (float)b1[2] + (float)b2[2] + (float)b3[2]) * inv;
        a.w = (a.w + (float)b1[3] + (float)b2[3] + (float)b3[3]) * inv;
        *(float4*)(out + ii) = a;
    }
}

// ---------------------------------------------------------------------------
// workspace layout helper (identical to R6)
// ---------------------------------------------------------------------------
#define WS_PTRS(ws)                                                   \
    _Float16* xh = (_Float16*)(ws);                                   \
    _Float16* Wt = (_Float16*)((ws) + (8ull  << 20));                 \
    _Float16* qh = (_Float16*)((ws) + (14ull << 20));                 \
    _Float16* kh = (_Float16*)((ws) + (22ull << 20));                 \
    _Float16* vt = (_Float16*)((ws) + (30ull << 20));                 \
    _Float16* P  = (_Float16*)((ws) + (38ull << 20));                 \
    float* rowsum_part = (float*)(ws);                                \
    _Float16* P1 = (_Float16*)((ws) + (2ull  << 20));                 \
    _Float16* P2 = (_Float16*)((ws) + (11ull << 20));                 \
    _Float16* P3 = (_Float16*)((ws) + (20ull << 20));

// ---------------------------------------------------------------------------
// Cooperative mega kernel: 5 phases with grid.sync(). Grid size G is chosen
// at launch from the occupancy query; all phases use stride-G task loops.
// ---------------------------------------------------------------------------
__global__ void __launch_bounds__(128, 2)
mega_kernel(const float* __restrict__ x,
            const float* __restrict__ W0,
            const float* __restrict__ W1,
            const float* __restrict__ W2,
            const float* __restrict__ bq,
            const float* __restrict__ bk,
            const float* __restrict__ bv,
            float* __restrict__ out,
            char* __restrict__ ws)
{
    __shared__ _Float16 ldsA[128 * 64];
    __shared__ _Float16 ldsB[128 * 64];
    WS_PTRS(ws)

    cooperative_groups::grid_group grid = cooperative_groups::this_grid();
    const int b = blockIdx.x;
    const int G = gridDim.x;

    // Phase 0: prep
    prep_x_body(G * 128, b * 128 + threadIdx.x, x, xh);
    prep_w_body(G, b, W0, W1, W2, Wt, (float*)ldsA);
    __threadfence();
    grid.sync();

    // Phase 1: QKV (768 tasks)
    for (int task = b; task < 768; task += G)
        task_qkv(task, xh, Wt, bq, bk, bv, qh, kh, vt, ldsA, ldsB);
    __threadfence();
    grid.sync();

    // Phase 2: S = exp(qk^T/32 - 8) + partial rowsums (1024 tasks)
    for (int task = b; task < 1024; task += G)
        task_s(task, qh, kh, P, rowsum_part, ldsA, ldsB);
    __threadfence();
    grid.sync();

    // Phase 3: PV split-K=4 (1024 tasks)
    for (int task = b; task < 1024; task += G)
        task_pv(task, P, vt, out, P1, P2, P3, ldsA, ldsB);
    __threadfence();
    grid.sync();

    // Phase 4: normalize (4096 rows)
    for (int row = b; row < NTOK; row += G)
        task_addinv(row, out, P1, P2, P3, rowsum_part);
}

// ---------------------------------------------------------------------------
// Fallback kernels (R6 path, same device bodies)
// ---------------------------------------------------------------------------
__global__ void __launch_bounds__(128) fb_prep(const float* __restrict__ x,
                                               const float* __restrict__ W0,
                                               const float* __restrict__ W1,
                                               const float* __restrict__ W2,
                                               _Float16* __restrict__ xh,
                                               _Float16* __restrict__ Wt)
{
    __shared__ float tile[32 * 33];
    prep_x_body(gridDim.x * 128, blockIdx.x * 128 + threadIdx.x, x, xh);
    prep_w_body(gridDim.x, blockIdx.x, W0, W1, W2, Wt, tile);
}

__global__ void __launch_bounds__(128, 2) fb_qkv(const _Float16* __restrict__ xh,
                                                 const _Float16* __restrict__ Wt,
                                                 const float* __restrict__ bq,
                                                 const float* __restrict__ bk,
                                                 const float* __restrict__ bv,
                                                 _Float16* __restrict__ qh,
                                                 _Float16* __restrict__ kh,
                                                 _Float16* __restrict__ vt)
{
    __shared__ _Float16 ldsA[128 * 64];
    __shared__ _Float16 ldsB[128 * 64];
    task_qkv(blockIdx.x, xh, Wt, bq, bk, bv, qh, kh, vt, ldsA, ldsB);
}

__global__ void __launch_bounds__(128, 2) fb_s(const _Float16* __restrict__ qh,
                                               const _Float16* __restrict__ kh,
                                               _Float16* __restrict__ P,
                                               float* __restrict__ rowsum_part)
{
    __shared__ _Float16 ldsA[128 * 64];
    __shared__ _Float16 ldsB[128 * 64];
    task_s(blockIdx.x, qh, kh, P, rowsum_part, ldsA, ldsB);
}

__global__ void __launch_bounds__(128, 2) fb_pv(const _Float16* __restrict__ P,
                                                const _Float16* __restrict__ vt,
                                                float* __restrict__ out,
                                                _Float16* __restrict__ P1,
                                                _Float16* __restrict__ P2,
                                                _Float16* __restrict__ P3)
{
    __shared__ _Float16 ldsA[128 * 64];
    __shared__ _Float16 ldsB[128 * 64];
    task_pv(blockIdx.x, P, vt, out, P1, P2, P3, ldsA, ldsB);
}

__global__ void __launch_bounds__(128) fb_addinv(float* __restrict__ out,
                                                 const _Float16* __restrict__ P1,
                                                 const _Float16* __restrict__ P2,
                                                 const _Float16* __restrict__ P3,
                                                 const float* __restrict__ rowsum_part)
{
    task_addinv(blockIdx.x, out, P1, P2, P3, rowsum_part);
}

// ---------------------------------------------------------------------------
// launch
// ---------------------------------------------------------------------------
extern "C" void kernel_launch(void* const* d_in, const int* in_sizes, int n_in,
                              void* d_out, int out_size, void* d_ws, size_t ws_size,
                              hipStream_t stream)
{
    const float* x  = (const float*)d_in[0];
    const float* Wq = (const float*)d_in[1];
    const float* Wk = (const float*)d_in[2];
    const float* Wv = (const float*)d_in[3];
    const float* bq = (const float*)d_in[4];
    const float* bk = (const float*)d_in[5];
    const float* bv = (const float*)d_in[6];
    float* out = (float*)d_out;
    char* ws = (char*)d_ws;
    WS_PTRS(ws)
    (void)xh; (void)Wt; (void)qh; (void)kh; (void)vt; (void)P;
    (void)rowsum_part; (void)P1; (void)P2; (void)P3;

    // Pick a cooperative grid the runtime will accept (pure query: capture-safe)
    int maxPerCU = 0;
    hipError_t qerr = hipOccupancyMaxActiveBlocksPerMultiprocessor(
        &maxPerCU, (const void*)mega_kernel, 128, 0);
    int G = 0;
    if (qerr == hipSuccess && maxPerCU > 0) {
        int cap = maxPerCU * 256;   // 256 CUs on MI355X
        G = (cap >= 1024) ? 1024 : (cap >= 768) ? 768 : (cap >= 512) ? 512
          : (cap >= 256) ? 256 : 0;
    }

    bool coop_ok = false;
    if (G >= 256) {
        void* args[] = { (void*)&x, (void*)&Wq, (void*)&Wk, (void*)&Wv,
                         (void*)&bq, (void*)&bk, (void*)&bv, (void*)&out,
                         (void*)&ws };
        hipError_t lerr = hipLaunchCooperativeKernel((void*)mega_kernel,
                                                     dim3(G), dim3(128),
                                                     args, 0, stream);
        coop_ok = (lerr == hipSuccess);
    }

    if (!coop_ok) {
        // R6 fallback path (verified: 216 us, absmax 9.77e-4)
        fb_prep<<<dim3(2048), 128, 0, stream>>>(x, Wq, Wk, Wv, xh, Wt);
        fb_qkv<<<dim3(768), 128, 0, stream>>>(xh, Wt, bq, bk, bv, qh, kh, vt);
        fb_s<<<dim3(1024), 128, 0, stream>>>(qh, kh, P, rowsum_part);
        fb_pv<<<dim3(1024), 128, 0, stream>>>(P, vt, out, P1, P2, P3);
        fb_addinv<<<dim3(NTOK), 128, 0, stream>>>(out, P1, P2, P3, rowsum_part);
    }
}

// Round 9
// 215.397 us; speedup vs baseline: 3.0575x; 3.0575x over previous
//
#include <hip/hip_runtime.h>
#include <hip/hip_fp16.h>
#include <cstdint>
#include <cstddef>

// ---------------------------------------------------------------------------
// SelfAttentionV2: out = softmax((x Wq + bq)(x Wk + bk)^T / 32) (x Wv + bv)
// N=4096, D=1024. fp32 in/out, fp16 MFMA internal.
// R9: back to multi-dispatch (coop falsified: 860us). QKV rebalanced to
//     exactly 2 blocks/CU via mixed-K wide grid: q,k = 256 full-K 128x256
//     tasks (blocks 0-255), v = 256 half-K tasks (blocks 256-511, split-K=2,
//     fp16 partials + combine kernel). S / PV / prep / add_inv are the
//     verified R6 bodies (numerics proven by R8's coop run: absmax 9.77e-4).
// ---------------------------------------------------------------------------

#define NTOK 4096
#define DIM  1024

typedef _Float16 half8  __attribute__((ext_vector_type(8)));
typedef _Float16 half4v __attribute__((ext_vector_type(4)));
typedef float    floatx4 __attribute__((ext_vector_type(4)));

#define GLOBAL_AS __attribute__((address_space(1)))
#define LDS_AS    __attribute__((address_space(3)))

__device__ __forceinline__ void lds_load16(const _Float16* gsrc, _Float16* ldst) {
    __builtin_amdgcn_global_load_lds((GLOBAL_AS void*)gsrc, (LDS_AS void*)ldst, 16, 0, 0);
}

// ---------------------------------------------------------------------------
// WIDE NT GEMM core (verbatim R4, verified): block 128(m) x 256(n), BK=64,
// swizzled LDS, 256 thr = 4 waves as 2m x 2n of 64x128 wave tiles.
// ---------------------------------------------------------------------------
__device__ __forceinline__ void gemm_wide_core(const _Float16* __restrict__ A,
                                               const _Float16* __restrict__ B,
                                               int K, int lda, int ldb,
                                               int m0, int n0,
                                               _Float16* ldsA, _Float16* ldsB,
                                               floatx4 acc[4][8])
{
    const int t    = threadIdx.x;
    const int lane = t & 63;
    const int wid  = t >> 6;
    const int wm   = (wid >> 1) * 64;
    const int wn   = (wid & 1) * 128;
    const int lrow = lane & 15;
    const int q    = lane >> 4;
    const int xk   = lrow & 7;

    const _Float16* asrc[4]; _Float16* adst[4];
    const _Float16* bsrc[8]; _Float16* bdst[8];
    #pragma unroll
    for (int i = 0; i < 4; ++i) {
        const int p = t + 256 * i, row = p >> 3;
        const int col = ((p & 7) ^ (row & 7)) * 8;
        asrc[i] = A + (size_t)(m0 + row) * lda + col;
        adst[i] = ldsA + p * 8;
    }
    #pragma unroll
    for (int i = 0; i < 8; ++i) {
        const int p = t + 256 * i, row = p >> 3;
        const int col = ((p & 7) ^ (row & 7)) * 8;
        bsrc[i] = B + (size_t)(n0 + row) * ldb + col;
        bdst[i] = ldsB + p * 8;
    }

    const _Float16* fa = ldsA + (wm + lrow) * 64;
    const _Float16* fb = ldsB + (wn + lrow) * 64;

    for (int k0 = 0; k0 < K; k0 += 64) {
        #pragma unroll
        for (int i = 0; i < 4; ++i) lds_load16(asrc[i] + k0, adst[i]);
        #pragma unroll
        for (int i = 0; i < 8; ++i) lds_load16(bsrc[i] + k0, bdst[i]);
        __syncthreads();

        #pragma unroll
        for (int s = 0; s < 2; ++s) {
            const int co = (((s * 4 + q) ^ xk) * 8);
            half8 af[4], bf[8];
            #pragma unroll
            for (int i = 0; i < 4; ++i) af[i] = *(const half8*)(fa + i * 1024 + co);
            #pragma unroll
            for (int i = 0; i < 8; ++i) bf[i] = *(const half8*)(fb + i * 1024 + co);
            #pragma unroll
            for (int ni = 0; ni < 8; ++ni)
                #pragma unroll
                for (int mi = 0; mi < 4; ++mi)
                    acc[mi][ni] = __builtin_amdgcn_mfma_f32_16x16x32_f16(
                        af[mi], bf[ni], acc[mi][ni], 0, 0, 0);
        }
        __syncthreads();
    }
}

// ---------------------------------------------------------------------------
// 2-WAVE NT GEMM core (verbatim R6/R8, verified): block 128x128, BK=64.
// ---------------------------------------------------------------------------
__device__ __forceinline__ void gemm_core2(const _Float16* __restrict__ A,
                                           const _Float16* __restrict__ B,
                                           int K, int lda, int ldb,
                                           int m0, int n0,
                                           _Float16* ldsA, _Float16* ldsB,
                                           floatx4 acc[4][8])
{
    const int t    = threadIdx.x;    // 0..127
    const int lane = t & 63;
    const int wid  = t >> 6;
    const int wm   = wid * 64;
    const int lrow = lane & 15;
    const int q    = lane >> 4;
    const int xk   = lrow & 7;

    const _Float16* asrc[8]; _Float16* adst[8];
    const _Float16* bsrc[8]; _Float16* bdst[8];
    #pragma unroll
    for (int i = 0; i < 8; ++i) {
        const int p = t + 128 * i, row = p >> 3;
        const int col = ((p & 7) ^ (row & 7)) * 8;
        asrc[i] = A + (size_t)(m0 + row) * lda + col;
        adst[i] = ldsA + p * 8;
        bsrc[i] = B + (size_t)(n0 + row) * ldb + col;
        bdst[i] = ldsB + p * 8;
    }

    const _Float16* fa = ldsA + (wm + lrow) * 64;
    const _Float16* fb = ldsB + lrow * 64;

    for (int k0 = 0; k0 < K; k0 += 64) {
        #pragma unroll
        for (int i = 0; i < 8; ++i) lds_load16(asrc[i] + k0, adst[i]);
        #pragma unroll
        for (int i = 0; i < 8; ++i) lds_load16(bsrc[i] + k0, bdst[i]);
        __syncthreads();

        #pragma unroll
        for (int s = 0; s < 2; ++s) {
            const int co = (((s * 4 + q) ^ xk) * 8);
            half8 af[4], bf[8];
            #pragma unroll
            for (int i = 0; i < 4; ++i) af[i] = *(const half8*)(fa + i * 1024 + co);
            #pragma unroll
            for (int i = 0; i < 8; ++i) bf[i] = *(const half8*)(fb + i * 1024 + co);
            #pragma unroll
            for (int ni = 0; ni < 8; ++ni)
                #pragma unroll
                for (int mi = 0; mi < 4; ++mi)
                    acc[mi][ni] = __builtin_amdgcn_mfma_f32_16x16x32_f16(
                        af[mi], bf[ni], acc[mi][ni], 0, 0, 0);
        }
        __syncthreads();
    }
}

// ---------------------------------------------------------------------------
// K0: prep. x fp32->fp16 (grid-strided) + W transpose+convert (3 matrices).
// ---------------------------------------------------------------------------
__global__ void __launch_bounds__(128) prep_kernel(const float* __restrict__ x,
                                                   const float* __restrict__ W0,
                                                   const float* __restrict__ W1,
                                                   const float* __restrict__ W2,
                                                   _Float16* __restrict__ xh,
                                                   _Float16* __restrict__ Wt)
{
    __shared__ float tile[32 * 33];
    const int t = threadIdx.x;
    const int G = gridDim.x;

    for (size_t idx = (size_t)blockIdx.x * 128 + t; idx < (size_t)NTOK * DIM / 4;
         idx += (size_t)G * 128) {
        size_t i = idx * 4;
        float4 v = *(const float4*)(x + i);
        half4v h;
        h[0] = (_Float16)v.x; h[1] = (_Float16)v.y;
        h[2] = (_Float16)v.z; h[3] = (_Float16)v.w;
        *(half4v*)(xh + i) = h;
    }

    const int tx = t & 31, ty = t >> 5;   // ty in [0,4)
    for (int w = blockIdx.x; w < 3072; w += G) {
        const int z = w >> 10, r = w & 1023;
        const int nb = (r & 31) * 32, kb = (r >> 5) * 32;
        const float* W = (z == 0) ? W0 : (z == 1) ? W1 : W2;
        _Float16* outw = Wt + (size_t)z * DIM * DIM;
        #pragma unroll
        for (int i = 0; i < 32; i += 4)
            tile[(ty + i) * 33 + tx] = W[(size_t)(kb + ty + i) * DIM + nb + tx];
        __syncthreads();
        #pragma unroll
        for (int i = 0; i < 32; i += 4)
            outw[(size_t)(nb + ty + i) * DIM + kb + tx] =
                (_Float16)tile[tx * 33 + ty + i];
        __syncthreads();
    }
}

// ---------------------------------------------------------------------------
// K1: QKV, mixed-K wide grid (512 blocks x 256 thr = 2 blocks/CU):
//   b in [0,256):   q (b<128) / k (b>=128), full K=1024, 128x256 tasks.
//   b in [256,512): v^T half-K tasks (split-K=2): h=(b-256)>>7 selects
//                   k-window; bias added in h==0 partial only.
// Dispatch order puts the 256 full-K blocks first (round-robin CU fill ->
// each CU gets one full + one half task => makespan ~1.5 T_block).
// ---------------------------------------------------------------------------
__global__ void __launch_bounds__(256, 2)
qkv_kernel(const _Float16* __restrict__ xh,
           const _Float16* __restrict__ Wt,
           const float* __restrict__ bq,
           const float* __restrict__ bk,
           const float* __restrict__ bv,
           _Float16* __restrict__ qh,
           _Float16* __restrict__ kh,
           _Float16* __restrict__ vt0,
           _Float16* __restrict__ vt1)
{
    __shared__ _Float16 ldsA[128 * 64];
    __shared__ _Float16 ldsB[256 * 64];

    const int b = blockIdx.x;

    const _Float16* A; const _Float16* B;
    const float* bias; _Float16* outm;
    int m0, n0, ldc, K, kstart; bool bias_by_row, do_bias;

    if (b < 256) {
        const int z = b >> 7;            // 0:q 1:k
        const int g = b & 127;
        const int xcd = g & 7;
        const int j   = g >> 3;          // 0..15
        const int mt  = xcd * 4 + (j & 3);   // 32 m-tiles
        const int nt  = j >> 2;              // 4 n-tiles of 256
        m0 = mt * 128; n0 = nt * 256; ldc = DIM;
        K = DIM; kstart = 0; bias_by_row = false; do_bias = true;
        A = xh;
        B = (z == 0) ? Wt : Wt + DIM * DIM;
        bias = (z == 0) ? bq : bk;
        outm = (z == 0) ? qh : kh;
    } else {
        const int h = (b - 256) >> 7;    // k-half 0/1
        const int g = b & 127;
        const int xcd = g & 7;
        const int j   = g >> 3;          // 0..15
        m0 = xcd * 128;                  // 8 m-tiles (d-dim)
        n0 = j * 256;                    // 16 n-tiles (tokens)
        ldc = NTOK;
        K = DIM / 2; kstart = h * (DIM / 2);
        bias_by_row = true; do_bias = (h == 0);
        A = Wt + 2 * DIM * DIM; B = xh; bias = bv;
        outm = (h == 0) ? vt0 : vt1;
    }

    floatx4 acc[4][8];
    #pragma unroll
    for (int mi = 0; mi < 4; ++mi)
        #pragma unroll
        for (int ni = 0; ni < 8; ++ni)
            #pragma unroll
            for (int r = 0; r < 4; ++r) acc[mi][ni][r] = 0.0f;

    gemm_wide_core(A + kstart, B + kstart, K, DIM, DIM, m0, n0, ldsA, ldsB, acc);

    const int lane = threadIdx.x & 63;
    const int wid  = threadIdx.x >> 6;
    const int wm   = (wid >> 1) * 64;
    const int wn   = (wid & 1) * 128;
    const int lrow = lane & 15;
    const int q    = lane >> 4;
    #pragma unroll
    for (int mi = 0; mi < 4; ++mi) {
        #pragma unroll
        for (int ni = 0; ni < 8; ++ni) {
            const int gm = m0 + wm + mi * 16 + q * 4;
            const int gn = n0 + wn + ni * 16 + lrow;
            const float bcol = (!do_bias || bias_by_row) ? 0.0f : bias[gn];
            #pragma unroll
            for (int r = 0; r < 4; ++r) {
                float bb = do_bias ? (bias_by_row ? bias[gm + r] : bcol) : 0.0f;
                outm[(size_t)(gm + r) * ldc + gn] = (_Float16)(acc[mi][ni][r] + bb);
            }
        }
    }
}

// ---------------------------------------------------------------------------
// K2: combine v partials: vt = vt0 + vt1 (fp16, fp32 add). 4M elems.
// ---------------------------------------------------------------------------
__global__ void __launch_bounds__(256) combine_v(const _Float16* __restrict__ vt0,
                                                 const _Float16* __restrict__ vt1,
                                                 _Float16* __restrict__ vt)
{
    size_t i = ((size_t)blockIdx.x * 256 + threadIdx.x) * 8;
    half8 a = *(const half8*)(vt0 + i);
    half8 b = *(const half8*)(vt1 + i);
    half8 o;
    #pragma unroll
    for (int k = 0; k < 8; ++k) o[k] = (_Float16)((float)a[k] + (float)b[k]);
    *(half8*)(vt + i) = o;
}

// ---------------------------------------------------------------------------
// K3: S-GEMM + fused exp + partial rowsums (verbatim R6 body, verified).
// grid 1024 (32mt x 32nt), XCD-banded.
// ---------------------------------------------------------------------------
__global__ void __launch_bounds__(128, 2) s_kernel(const _Float16* __restrict__ qh,
                                                   const _Float16* __restrict__ kh,
                                                   _Float16* __restrict__ P,
                                                   float* __restrict__ rowsum_part)
{
    __shared__ _Float16 ldsA[128 * 64];
    __shared__ _Float16 ldsB[128 * 64];

    const int f   = blockIdx.x;
    const int xcd = f & 7;
    const int j   = f >> 3;
    const int mt  = xcd * 4 + (j & 3);
    const int nt  = j >> 2;
    const int m0  = mt * 128;
    const int n0  = nt * 128;

    floatx4 acc[4][8];
    #pragma unroll
    for (int mi = 0; mi < 4; ++mi)
        #pragma unroll
        for (int ni = 0; ni < 8; ++ni)
            #pragma unroll
            for (int r = 0; r < 4; ++r) acc[mi][ni][r] = 0.0f;

    gemm_core2(qh, kh, DIM, DIM, DIM, m0, n0, ldsA, ldsB, acc);

    const int lane = threadIdx.x & 63;
    const int wm   = (threadIdx.x >> 6) * 64;
    const int lrow = lane & 15;
    const int q    = lane >> 4;

    #pragma unroll
    for (int mi = 0; mi < 4; ++mi) {
        #pragma unroll
        for (int r = 0; r < 4; ++r) {
            const int gm = m0 + wm + mi * 16 + q * 4 + r;
            float rs = 0.0f;
            #pragma unroll
            for (int ni = 0; ni < 8; ++ni) {
                const int gn = n0 + ni * 16 + lrow;
                float e = __expf(acc[mi][ni][r] * 0.03125f - 8.0f);
                P[(size_t)gm * NTOK + gn] = (_Float16)e;
                rs += e;
            }
            rs += __shfl_xor(rs, 1, 64);
            rs += __shfl_xor(rs, 2, 64);
            rs += __shfl_xor(rs, 4, 64);
            rs += __shfl_xor(rs, 8, 64);
            if (lrow == 0) rowsum_part[(size_t)gm * 32 + nt] = rs;
        }
    }
}

// ---------------------------------------------------------------------------
// K4: PV split-K=4 (verbatim R6 body, verified). grid 1024 flat.
// ---------------------------------------------------------------------------
__global__ void __launch_bounds__(128, 2) pv_kernel(const _Float16* __restrict__ P,
                                                    const _Float16* __restrict__ vt,
                                                    float* __restrict__ out,
                                                    _Float16* __restrict__ P1,
                                                    _Float16* __restrict__ P2,
                                                    _Float16* __restrict__ P3)
{
    __shared__ _Float16 ldsA[128 * 64];
    __shared__ _Float16 ldsB[128 * 64];

    const int task = blockIdx.x;
    const int z   = task >> 8;
    const int g   = task & 255;
    const int xcd = g & 7;
    const int j   = g >> 3;
    const int mt  = xcd * 4 + (j & 3);
    const int nt  = j >> 2;
    const int m0  = mt * 128;
    const int n0  = nt * 128;
    const int kstart = z * (NTOK / 4);

    floatx4 acc[4][8];
    #pragma unroll
    for (int mi = 0; mi < 4; ++mi)
        #pragma unroll
        for (int ni = 0; ni < 8; ++ni)
            #pragma unroll
            for (int r = 0; r < 4; ++r) acc[mi][ni][r] = 0.0f;

    gemm_core2(P + kstart, vt + kstart, NTOK / 4, NTOK, NTOK, m0, n0,
               ldsA, ldsB, acc);

    const int lane = threadIdx.x & 63;
    const int wm   = (threadIdx.x >> 6) * 64;
    const int lrow = lane & 15;
    const int q    = lane >> 4;

    _Float16* ph = (z == 1) ? P1 : (z == 2) ? P2 : P3;
    #pragma unroll
    for (int mi = 0; mi < 4; ++mi) {
        #pragma unroll
        for (int ni = 0; ni < 8; ++ni) {
            const int gm = m0 + wm + mi * 16 + q * 4;
            const int gn = n0 + ni * 16 + lrow;
            #pragma unroll
            for (int r = 0; r < 4; ++r) {
                if (z == 0) out[(size_t)(gm + r) * DIM + gn] = acc[mi][ni][r];
                else        ph[(size_t)(gm + r) * DIM + gn] = (_Float16)acc[mi][ni][r];
            }
        }
    }
}

// ---------------------------------------------------------------------------
// K5: out = (out + P1 + P2 + P3) / rowsum (verbatim R6 body, verified).
// ---------------------------------------------------------------------------
__global__ void __launch_bounds__(128) add_inv_kernel(float* __restrict__ out,
                                                      const _Float16* __restrict__ P1,
                                                      const _Float16* __restrict__ P2,
                                                      const _Float16* __restrict__ P3,
                                                      const float* __restrict__ rowsum_part)
{
    const int row = blockIdx.x;
    const int t = threadIdx.x;
    float v = rowsum_part[(size_t)row * 32 + (t & 31)];
    v += __shfl_xor(v, 16, 64);
    v += __shfl_xor(v, 8, 64);
    v += __shfl_xor(v, 4, 64);
    v += __shfl_xor(v, 2, 64);
    v += __shfl_xor(v, 1, 64);
    const float inv = 1.0f / v;

    size_t i = (size_t)row * DIM + (size_t)t * 8;
    #pragma unroll
    for (int h = 0; h < 2; ++h) {
        size_t ii = i + h * 4;
        float4 a = *(const float4*)(out + ii);
        half4v b1 = *(const half4v*)(P1 + ii);
        half4v b2 = *(const half4v*)(P2 + ii);
        half4v b3 = *(const half4v*)(P3 + ii);
        a.x = (a.x + (float)b1[0] + (float)b2[0] + (float)b3[0]) * inv;
        a.y = (a.y + (float)b1[1] + (float)b2[1] + (float)b3[1]) * inv;
        a.z = (a.z + (float)b1[2] + (float)b2[2] + (float)b3[2]) * inv;
        a.w = (a.w + (float)b1[3] + (float)b2[3] + (float)b3[3]) * inv;
        *(float4*)(out + ii) = a;
    }
}

// ---------------------------------------------------------------------------
// launch
// ---------------------------------------------------------------------------
extern "C" void kernel_launch(void* const* d_in, const int* in_sizes, int n_in,
                              void* d_out, int out_size, void* d_ws, size_t ws_size,
                              hipStream_t stream)
{
    const float* x  = (const float*)d_in[0];
    const float* Wq = (const float*)d_in[1];
    const float* Wk = (const float*)d_in[2];
    const float* Wv = (const float*)d_in[3];
    const float* bq = (const float*)d_in[4];
    const float* bk = (const float*)d_in[5];
    const float* bv = (const float*)d_in[6];
    float* out = (float*)d_out;
    char* ws = (char*)d_ws;

    // workspace layout (70 MB peak):
    //   0..8    xh   (dead after QKV)      -> rowsum_part @0 (512 KB, S phase)
    //   8..14   Wt   (dead after QKV)      -> P1 @2..10 (PV phase)
    //  14..22   qh   (dead after S)        -> P2 @11..19
    //  22..30   kh   (dead after S)        -> P3 @20..28
    //  30..38   vt   (alive through PV)
    //  38..46   vt0  (dead after combine; P overwrites in S phase)
    //  46..54   vt1  (dead after combine; P overwrites in S phase)
    //  38..70   P    (written in S, after vt0/vt1 dead)
    _Float16* xh  = (_Float16*)(ws);
    _Float16* Wt  = (_Float16*)(ws + (8ull  << 20));
    _Float16* qh  = (_Float16*)(ws + (14ull << 20));
    _Float16* kh  = (_Float16*)(ws + (22ull << 20));
    _Float16* vt  = (_Float16*)(ws + (30ull << 20));
    _Float16* vt0 = (_Float16*)(ws + (38ull << 20));
    _Float16* vt1 = (_Float16*)(ws + (46ull << 20));
    _Float16* P   = (_Float16*)(ws + (38ull << 20));
    float* rowsum_part = (float*)(ws);
    _Float16* P1  = (_Float16*)(ws + (2ull  << 20));
    _Float16* P2  = (_Float16*)(ws + (11ull << 20));
    _Float16* P3  = (_Float16*)(ws + (20ull << 20));

    prep_kernel<<<dim3(2048), 128, 0, stream>>>(x, Wq, Wk, Wv, xh, Wt);
    qkv_kernel<<<dim3(512), 256, 0, stream>>>(xh, Wt, bq, bk, bv, qh, kh, vt0, vt1);
    combine_v<<<dim3(NTOK * DIM / (256 * 8)), 256, 0, stream>>>(vt0, vt1, vt);
    s_kernel<<<dim3(1024), 128, 0, stream>>>(qh, kh, P, rowsum_part);
    pv_kernel<<<dim3(1024), 128, 0, stream>>>(P, vt, out, P1, P2, P3);
    add_inv_kernel<<<dim3(NTOK), 128, 0, stream>>>(out, P1, P2, P3, rowsum_part);
}